// Round 2
// baseline (1374.095 us; speedup 1.0000x reference)
//
#include <hip/hip_runtime.h>
#include <cstddef>

// ---------------------------------------------------------------------------
// PolyaAKT interaction embedder, MI355X/gfx950.  Inputs fp32, output fp32.
// Control path (logits/GRU) in fp64 VALU for argmax fidelity; value path
// (experts/LN/proj) in bf16 MFMA.  Per-q dedup: q_summary/gru_in/xg/lq and
// expert outputs depend only on q (10000 values), not tokens (32768).
// All scratch in __device__ globals (ws_size unknown -> don't trust d_ws).
// ---------------------------------------------------------------------------

#define NQ 10000
#define TT 32768   // B*S

typedef __attribute__((ext_vector_type(8))) short bf16x8;
typedef __attribute__((ext_vector_type(4))) float f32x4;

__device__ double g_qs  [NQ * 256];      // q_summary (relu'd), fp64
__device__ double g_xgq [NQ * 192];      // gru_in_q @ W_ih^T
__device__ double g_xgr [2 * 192];       // (resp@red2 + red_b) @ W_ih^T + b_ih
__device__ double g_xg0 [192];           // start_token @ W_ih^T + b_ih
__device__ double g_lq  [NQ * 4];        // qs @ wgate[0:256]
__device__ double g_m   [TT * 64];       // GRU hidden per token
__device__ int    g_top1[TT];
__device__ unsigned short g_w1t  [4 * 256 * 256];  // bf16 [e][n][k]
__device__ unsigned short g_w2t  [4 * 256 * 256];
__device__ unsigned short g_projt[512 * 256];      // bf16 [n(cor|inc)][k]
__device__ unsigned short g_qf   [NQ * 4 * 256];   // LN'd expert out, bf16

__device__ __forceinline__ float bf2f(unsigned short x) {
  return __uint_as_float(((unsigned)x) << 16);
}
__device__ __forceinline__ unsigned short f2bf(float f) {
  unsigned u = __float_as_uint(f);
  u += 0x7FFFu + ((u >> 16) & 1u);   // RNE
  return (unsigned short)(u >> 16);
}
__device__ __forceinline__ f32x4 mfma16(bf16x8 a, bf16x8 b, f32x4 c) {
  return __builtin_amdgcn_mfma_f32_16x16x32_bf16(a, b, c, 0, 0, 0);
}

// ---------------------------------------------------------------------------
// prep: bf16 transposed weight tables + fp64 folds (xg_r, xg0).
// ---------------------------------------------------------------------------
__global__ void __launch_bounds__(256) prep_kernel(
    const float* __restrict__ expert_w1, const float* __restrict__ expert_w2,
    const float* __restrict__ proj_cor_w, const float* __restrict__ proj_inc_w,
    const float* __restrict__ resp_table, const float* __restrict__ reducer_w,
    const float* __restrict__ reducer_b,  const float* __restrict__ start_token,
    const float* __restrict__ gru_w_ih,   const float* __restrict__ gru_b_ih)
{
  __shared__ double red2f[128];   // [rr][j]
  const int tid = threadIdx.x;
  if (blockIdx.x == 0) {
    if (tid < 128) {
      const int rr = tid >> 6, j = tid & 63;
      double acc = (double)reducer_b[j];
      for (int k = 0; k < 256; ++k)
        acc += (double)resp_table[rr * 256 + k] *
               (double)reducer_w[(256 + k) * 64 + j];
      red2f[tid] = acc;
    }
    __syncthreads();
    if (tid < 192) {
      const double bih = (double)gru_b_ih[tid];
      double a0 = bih, a1 = bih, a2 = bih;
      for (int j = 0; j < 64; ++j) {
        const double w = (double)gru_w_ih[tid * 64 + j];
        a0 += red2f[j] * w;
        a1 += red2f[64 + j] * w;
        a2 += (double)start_token[j] * w;
      }
      g_xgr[tid] = a0; g_xgr[192 + tid] = a1; g_xg0[tid] = a2;
    }
  }
  const int idx0 = blockIdx.x * 256 + tid;
  const int stride = gridDim.x * 256;
  for (int i = idx0; i < 4 * 256 * 256; i += stride) {
    const int e = i >> 16, rem = i & 65535, n = rem >> 8, k = rem & 255;
    g_w1t[i] = f2bf(expert_w1[e * 65536 + k * 256 + n]);
    g_w2t[i] = f2bf(expert_w2[e * 65536 + k * 256 + n]);
  }
  for (int i = idx0; i < 512 * 256; i += stride) {
    const int n = i >> 8, k = i & 255;
    g_projt[i] = f2bf((n < 256) ? proj_cor_w[k * 256 + n]
                                : proj_inc_w[k * 256 + (n - 256)]);
  }
}

// ---------------------------------------------------------------------------
// qsk: fp64 GEMM  qs[q][n] = relu( emb_row_q(1024) . adapter_w[:,n] + b[n] )
// M-tile 64 (grid.x=157, clamp), N-tile 64 (grid.y=4), K chunks of 32.
// ---------------------------------------------------------------------------
__global__ void __launch_bounds__(256) qsk_kernel(
    const float* __restrict__ emb, const float* __restrict__ adapter_w,
    const float* __restrict__ adapter_b)
{
  __shared__ __align__(16) float As[64][33];
  __shared__ __align__(16) float Bs[32][65];
  const int tid = threadIdx.x;
  const int q0 = blockIdx.x * 64;
  const int n0 = blockIdx.y * 64;
  const int ty = tid >> 4, tx = tid & 15;

  double acc[4][4];
#pragma unroll
  for (int i = 0; i < 4; ++i)
#pragma unroll
    for (int j = 0; j < 4; ++j) acc[i][j] = 0.0;

  const int arow = tid >> 2, aks = (tid & 3) * 8;
  const int qa = min(q0 + arow, NQ - 1);
  const int bkk = tid >> 3, bns = (tid & 7) * 8;

  for (int kc = 0; kc < 1024; kc += 32) {
    f32x4 av0 = *(const f32x4*)(emb + (size_t)qa * 1024 + kc + aks);
    f32x4 av1 = *(const f32x4*)(emb + (size_t)qa * 1024 + kc + aks + 4);
    f32x4 bv0 = *(const f32x4*)(adapter_w + (size_t)(kc + bkk) * 256 + n0 + bns);
    f32x4 bv1 = *(const f32x4*)(adapter_w + (size_t)(kc + bkk) * 256 + n0 + bns + 4);
    __syncthreads();
#pragma unroll
    for (int i = 0; i < 4; ++i) { As[arow][aks + i] = av0[i]; As[arow][aks + 4 + i] = av1[i]; }
#pragma unroll
    for (int i = 0; i < 4; ++i) { Bs[bkk][bns + i] = bv0[i]; Bs[bkk][bns + 4 + i] = bv1[i]; }
    __syncthreads();
#pragma unroll 4
    for (int kk = 0; kk < 32; ++kk) {
      double a[4], b[4];
#pragma unroll
      for (int i = 0; i < 4; ++i) a[i] = (double)As[ty * 4 + i][kk];
#pragma unroll
      for (int j = 0; j < 4; ++j) b[j] = (double)Bs[kk][tx * 4 + j];
#pragma unroll
      for (int i = 0; i < 4; ++i)
#pragma unroll
        for (int j = 0; j < 4; ++j) acc[i][j] = fma(a[i], b[j], acc[i][j]);
    }
  }
#pragma unroll
  for (int i = 0; i < 4; ++i) {
    const int qrow = q0 + ty * 4 + i;
    if (qrow < NQ) {
#pragma unroll
      for (int j = 0; j < 4; ++j) {
        const int n = n0 + tx * 4 + j;
        double v = acc[i][j] + (double)adapter_b[n];
        g_qs[(size_t)qrow * 256 + n] = v > 0.0 ? v : 0.0;
      }
    }
  }
}

// ---------------------------------------------------------------------------
// smallk: per q -> gru_in_q(64), xg_q(192), lq(4).  One block per q.
// ---------------------------------------------------------------------------
__global__ void __launch_bounds__(256) smallk_kernel(
    const float* __restrict__ reducer_w, const float* __restrict__ gru_w_ih,
    const float* __restrict__ wgate_w)
{
  __shared__ double qsr[256];
  __shared__ double ps[4][64];
  __shared__ double gi[64];
  const int tid = threadIdx.x;
  const int q = blockIdx.x;
  qsr[tid] = g_qs[(size_t)q * 256 + tid];
  __syncthreads();
  {
    const int j = tid & 63, h = tid >> 6;
    double a = 0.0;
    for (int k = h * 64; k < h * 64 + 64; ++k)
      a = fma(qsr[k], (double)reducer_w[k * 64 + j], a);
    ps[h][j] = a;
  }
  __syncthreads();
  if (tid < 64) gi[tid] = (ps[0][tid] + ps[1][tid]) + (ps[2][tid] + ps[3][tid]);
  if (tid >= 64 && tid < 68) {
    const int e = tid - 64;
    double a = 0.0;
    for (int k = 0; k < 256; ++k)
      a = fma(qsr[k], (double)wgate_w[k * 4 + e], a);
    g_lq[(size_t)q * 4 + e] = a;
  }
  __syncthreads();
  if (tid < 192) {
    double a = 0.0;
    for (int j = 0; j < 64; ++j)
      a = fma(gi[j], (double)gru_w_ih[tid * 64 + j], a);
    g_xgq[(size_t)q * 192 + tid] = a;
  }
}

// ---------------------------------------------------------------------------
// gru: fp64 scan.  64 blocks (one sequence) x 192 threads (gate r/z/n, lane j).
// ---------------------------------------------------------------------------
__global__ void __launch_bounds__(192) gru_kernel(
    const int* __restrict__ q, const int* __restrict__ r,
    const float* __restrict__ whh, const float* __restrict__ bhh)
{
  __shared__ __align__(16) double h_l[64];
  __shared__ double rz[128];
  const int tid = threadIdx.x;          // g*64 + j
  const int g = tid >> 6, j = tid & 63;
  const int b = blockIdx.x;

  double W[64];
#pragma unroll
  for (int k = 0; k < 64; ++k) W[k] = (double)whh[(size_t)tid * 64 + k];
  const double bv = (double)bhh[tid];
  if (tid < 64) h_l[tid] = 0.0;
  __syncthreads();

  double xv = g_xg0[tid];               // step 0 input (start token)
  int qn = q[b * 512], rn = r[b * 512];
  for (int s = 0; s < 512; ++s) {
    // prefetch x for step s+1 = token (b, s)
    double xnext = 0.0;
    if (s < 511)
      xnext = g_xgq[(size_t)qn * 192 + tid] + g_xgr[rn * 192 + tid];
    const int sn = s + 1;
    if (sn < 511) { qn = q[b * 512 + sn]; rn = r[b * 512 + sn]; }

    double a0 = 0.0, a1 = 0.0, a2 = 0.0, a3 = 0.0;
#pragma unroll
    for (int k = 0; k < 16; ++k) {
      a0 = fma(W[4 * k + 0], h_l[4 * k + 0], a0);
      a1 = fma(W[4 * k + 1], h_l[4 * k + 1], a1);
      a2 = fma(W[4 * k + 2], h_l[4 * k + 2], a2);
      a3 = fma(W[4 * k + 3], h_l[4 * k + 3], a3);
    }
    const double hg = bv + ((a0 + a1) + (a2 + a3));
    if (g < 2) rz[tid] = 1.0 / (1.0 + exp(-(xv + hg)));
    __syncthreads();
    if (g == 2) {
      const double rg = rz[j], zg = rz[64 + j];
      const double ng = tanh(xv + rg * hg);
      const double hn = (1.0 - zg) * ng + zg * h_l[j];
      h_l[j] = hn;
      g_m[((size_t)b * 512 + s) * 64 + j] = hn;
    }
    __syncthreads();
    xv = xnext;
  }
}

// ---------------------------------------------------------------------------
// top1: logits = lq[q_t] + m_t @ wgate[256:320] + wgate_b ; first-max argmax.
// ---------------------------------------------------------------------------
__global__ void __launch_bounds__(256) top1_kernel(
    const int* __restrict__ q,
    const float* __restrict__ wgate_w, const float* __restrict__ wgate_b)
{
  __shared__ double w2[256];   // [j][e]
  const int tid = threadIdx.x;
  w2[tid] = (double)wgate_w[1024 + tid];
  __syncthreads();
  const int t = blockIdx.x * 256 + tid;
  const int qv = q[t];
  double l0 = g_lq[(size_t)qv * 4 + 0] + (double)wgate_b[0];
  double l1 = g_lq[(size_t)qv * 4 + 1] + (double)wgate_b[1];
  double l2 = g_lq[(size_t)qv * 4 + 2] + (double)wgate_b[2];
  double l3 = g_lq[(size_t)qv * 4 + 3] + (double)wgate_b[3];
  const double* mr = g_m + (size_t)t * 64;
  for (int jj = 0; jj < 64; ++jj) {
    const double mv = mr[jj];
    l0 = fma(mv, w2[jj * 4 + 0], l0);
    l1 = fma(mv, w2[jj * 4 + 1], l1);
    l2 = fma(mv, w2[jj * 4 + 2], l2);
    l3 = fma(mv, w2[jj * 4 + 3], l3);
  }
  int bi = 0; double bvv = l0;
  if (l1 > bvv) { bvv = l1; bi = 1; }
  if (l2 > bvv) { bvv = l2; bi = 2; }
  if (l3 > bvv) { bvv = l3; bi = 3; }
  g_top1[t] = bi;
}

// ---------------------------------------------------------------------------
// kernelE: per 32 q-values: stage emb rows as bf16; for each expert e:
// h1=relu(qr_e@W1+b1) -> out=h1@W2+b2 -> LN -> qf[q][e] bf16.
// ---------------------------------------------------------------------------
__global__ void __launch_bounds__(128) kernelE(
    const float* __restrict__ emb,
    const float* __restrict__ b1, const float* __restrict__ b2,
    const float* __restrict__ lng, const float* __restrict__ lnb)
{
  __shared__ __align__(16) unsigned short QR[32 * 1032];
  __shared__ __align__(16) unsigned short H1[32 * 264];
  __shared__ __align__(16) unsigned short EO[32 * 264];
  const int tid = threadIdx.x;
  const int t0 = blockIdx.x * 32;
  const int w = tid >> 6;
  const int lane = tid & 63;
  const int l15 = lane & 15;
  const int quad = lane >> 4;

  // stage 32 emb rows (fp32 -> bf16)
  for (int c = 0; c < 64; ++c) {
    const int idx = c * 128 + tid;           // float4 index: 8192 total
    const int row = idx >> 8, col4 = idx & 255;
    const int qv = min(t0 + row, NQ - 1);
    f32x4 v = *(const f32x4*)(emb + (size_t)qv * 1024 + col4 * 4);
    unsigned a = ((unsigned)f2bf(v[1]) << 16) | f2bf(v[0]);
    unsigned bb = ((unsigned)f2bf(v[3]) << 16) | f2bf(v[2]);
    *(uint2*)&QR[row * 1032 + col4 * 4] = make_uint2(a, bb);
  }
  __syncthreads();

  const f32x4 z4 = {0.f, 0.f, 0.f, 0.f};
  const int n0 = w * 128;

  for (int e = 0; e < 4; ++e) {
    // ---- layer 1 ----
    f32x4 acc[2][8];
#pragma unroll
    for (int a = 0; a < 2; ++a)
#pragma unroll
      for (int bq = 0; bq < 8; ++bq) acc[a][bq] = z4;
#pragma unroll
    for (int ks = 0; ks < 8; ++ks) {
      const int koff = e * 256 + ks * 32 + quad * 8;
      bf16x8 a0 = *(const bf16x8*)&QR[l15 * 1032 + koff];
      bf16x8 a1 = *(const bf16x8*)&QR[(16 + l15) * 1032 + koff];
      const int kb = ks * 32 + quad * 8;
#pragma unroll
      for (int nt = 0; nt < 8; ++nt) {
        bf16x8 bbv = *(const bf16x8*)(g_w1t + (size_t)e * 65536 +
                                      (size_t)(n0 + nt * 16 + l15) * 256 + kb);
        acc[0][nt] = mfma16(a0, bbv, acc[0][nt]);
        acc[1][nt] = mfma16(a1, bbv, acc[1][nt]);
      }
    }
#pragma unroll
    for (int nt = 0; nt < 8; ++nt) {
      const int n = n0 + nt * 16 + l15;
      const float b1v = b1[e * 256 + n];
#pragma unroll
      for (int mt = 0; mt < 2; ++mt)
#pragma unroll
        for (int rg = 0; rg < 4; ++rg) {
          const int m = mt * 16 + quad * 4 + rg;
          H1[m * 264 + n] = f2bf(fmaxf(acc[mt][nt][rg] + b1v, 0.f));
        }
    }
    __syncthreads();
    // ---- layer 2 ----
    f32x4 acc2[2][8];
#pragma unroll
    for (int a = 0; a < 2; ++a)
#pragma unroll
      for (int bq = 0; bq < 8; ++bq) acc2[a][bq] = z4;
#pragma unroll
    for (int ks = 0; ks < 8; ++ks) {
      const int koff = ks * 32 + quad * 8;
      bf16x8 a0 = *(const bf16x8*)&H1[l15 * 264 + koff];
      bf16x8 a1 = *(const bf16x8*)&H1[(16 + l15) * 264 + koff];
#pragma unroll
      for (int nt = 0; nt < 8; ++nt) {
        bf16x8 bbv = *(const bf16x8*)(g_w2t + (size_t)e * 65536 +
                                      (size_t)(n0 + nt * 16 + l15) * 256 + koff);
        acc2[0][nt] = mfma16(a0, bbv, acc2[0][nt]);
        acc2[1][nt] = mfma16(a1, bbv, acc2[1][nt]);
      }
    }
#pragma unroll
    for (int nt = 0; nt < 8; ++nt) {
      const int n = n0 + nt * 16 + l15;
      const float b2v = b2[e * 256 + n];
#pragma unroll
      for (int mt = 0; mt < 2; ++mt)
#pragma unroll
        for (int rg = 0; rg < 4; ++rg) {
          const int m = mt * 16 + quad * 4 + rg;
          EO[m * 264 + n] = f2bf(acc2[mt][nt][rg] + b2v);
        }
    }
    __syncthreads();
    // ---- LayerNorm -> qf[qv][e] (4 threads per row) ----
    {
      const int m = tid >> 2;
      const int sub = tid & 3;
      float sx = 0.f, sxx = 0.f;
#pragma unroll
      for (int i = 0; i < 8; ++i) {
        bf16x8 v = *(const bf16x8*)&EO[m * 264 + sub * 64 + i * 8];
#pragma unroll
        for (int c = 0; c < 8; ++c) {
          const float f = bf2f((unsigned short)v[c]);
          sx += f; sxx += f * f;
        }
      }
      sx += __shfl_xor(sx, 1); sxx += __shfl_xor(sxx, 1);
      sx += __shfl_xor(sx, 2); sxx += __shfl_xor(sxx, 2);
      const float mu = sx * (1.f / 256.f);
      const float var = sxx * (1.f / 256.f) - mu * mu;
      const float inv = 1.f / sqrtf(var + 1e-5f);
      if (t0 + m < NQ) {
        const size_t base = ((size_t)(t0 + m) * 4 + e) * 256;
#pragma unroll
        for (int i = 0; i < 8; ++i) {
          const int dbase = sub * 64 + i * 8;
          bf16x8 v = *(const bf16x8*)&EO[m * 264 + dbase];
          bf16x8 ov;
#pragma unroll
          for (int c = 0; c < 8; ++c) {
            const int d = dbase + c;
            const float f = bf2f((unsigned short)v[c]);
            ov[c] = (short)f2bf(lng[d] * (f - mu) * inv + lnb[d]);
          }
          *(bf16x8*)(g_qf + base + dbase) = ov;
        }
      }
    }
    __syncthreads();
  }
}

// ---------------------------------------------------------------------------
// kernelF: per 32 tokens: gather qf[q_t][top1_t] -> q_fused out (fp32) and
// LDS; proj (cor|inc) bf16 MFMA; qa_fused by r.  out is float*.
// ---------------------------------------------------------------------------
__global__ void __launch_bounds__(128) kernelF(
    const int* __restrict__ q, const int* __restrict__ r,
    const float* __restrict__ pcb, const float* __restrict__ pib,
    float* __restrict__ out)
{
  __shared__ __align__(16) unsigned short QF[32 * 264];
  __shared__ int rv_l[32];
  const int tid = threadIdx.x;
  const int t0 = blockIdx.x * 32;
  const int w = tid >> 6;
  const int lane = tid & 63;
  const int l15 = lane & 15;
  const int quad = lane >> 4;
  if (tid < 32) rv_l[tid] = r[t0 + tid];
  __syncthreads();

  {
    const int m = tid >> 2;
    const size_t row = ((size_t)q[t0 + m] * 4 + g_top1[t0 + m]) * 256;
#pragma unroll
    for (int i = 0; i < 8; ++i) {
      const int dbase = (tid & 3) * 64 + i * 8;
      bf16x8 v = *(const bf16x8*)(g_qf + row + dbase);
      *(bf16x8*)&QF[m * 264 + dbase] = v;
      f32x4 f0, f1;
#pragma unroll
      for (int c = 0; c < 4; ++c) f0[c] = bf2f((unsigned short)v[c]);
#pragma unroll
      for (int c = 0; c < 4; ++c) f1[c] = bf2f((unsigned short)v[4 + c]);
      *(f32x4*)(out + (size_t)(t0 + m) * 256 + dbase) = f0;
      *(f32x4*)(out + (size_t)(t0 + m) * 256 + dbase + 4) = f1;
    }
  }
  __syncthreads();

  const f32x4 z4 = {0.f, 0.f, 0.f, 0.f};
  const int n0 = w * 128;
  for (int ph = 0; ph < 2; ++ph) {
    f32x4 acc[2][8];
#pragma unroll
    for (int a = 0; a < 2; ++a)
#pragma unroll
      for (int bq = 0; bq < 8; ++bq) acc[a][bq] = z4;
#pragma unroll
    for (int ks = 0; ks < 8; ++ks) {
      const int koff = ks * 32 + quad * 8;
      bf16x8 a0 = *(const bf16x8*)&QF[l15 * 264 + koff];
      bf16x8 a1 = *(const bf16x8*)&QF[(16 + l15) * 264 + koff];
#pragma unroll
      for (int nt = 0; nt < 8; ++nt) {
        bf16x8 bbv = *(const bf16x8*)(g_projt +
            (size_t)(ph * 256 + n0 + nt * 16 + l15) * 256 + koff);
        acc[0][nt] = mfma16(a0, bbv, acc[0][nt]);
        acc[1][nt] = mfma16(a1, bbv, acc[1][nt]);
      }
    }
    const float* pbb = ph ? pib : pcb;
    const int want = ph ? 0 : 1;
#pragma unroll
    for (int nt = 0; nt < 8; ++nt) {
      const int n = n0 + nt * 16 + l15;
      const float pbv = pbb[n];
#pragma unroll
      for (int mt = 0; mt < 2; ++mt)
#pragma unroll
        for (int rg = 0; rg < 4; ++rg) {
          const int m = mt * 16 + quad * 4 + rg;
          if (rv_l[m] == want)
            out[(size_t)TT * 256 + (size_t)(t0 + m) * 256 + n] =
                acc[mt][nt][rg] + pbv;
        }
    }
  }
}

// ---------------------------------------------------------------------------
extern "C" void kernel_launch(void* const* d_in, const int* in_sizes, int n_in,
                              void* d_out, int out_size, void* d_ws, size_t ws_size,
                              hipStream_t stream)
{
  const int*   q   = (const int*)d_in[0];
  const int*   r   = (const int*)d_in[1];
  const float* emb = (const float*)d_in[2];
  const float* ew1 = (const float*)d_in[3];
  const float* eb1 = (const float*)d_in[4];
  const float* ew2 = (const float*)d_in[5];
  const float* eb2 = (const float*)d_in[6];
  const float* aw  = (const float*)d_in[7];
  const float* ab  = (const float*)d_in[8];
  const float* rw  = (const float*)d_in[9];
  const float* rb  = (const float*)d_in[10];
  const float* st  = (const float*)d_in[11];
  const float* wih = (const float*)d_in[12];
  const float* whh = (const float*)d_in[13];
  const float* bih = (const float*)d_in[14];   // folded in prep via g_xgr/g_xg0
  const float* bhh = (const float*)d_in[15];
  const float* wgw = (const float*)d_in[16];
  const float* wgb = (const float*)d_in[17];
  const float* lng = (const float*)d_in[18];
  const float* lnb = (const float*)d_in[19];
  const float* resp= (const float*)d_in[20];
  const float* pcw = (const float*)d_in[21];
  const float* pcb = (const float*)d_in[22];
  const float* piw = (const float*)d_in[23];
  const float* pib = (const float*)d_in[24];
  float* out = (float*)d_out;
  (void)bih; (void)in_sizes; (void)n_in; (void)d_ws; (void)ws_size; (void)out_size;

  prep_kernel<<<64, 256, 0, stream>>>(ew1, ew2, pcw, piw, resp, rw, rb, st, wih, bih);
  qsk_kernel<<<dim3(157, 4), 256, 0, stream>>>(emb, aw, ab);
  smallk_kernel<<<NQ, 256, 0, stream>>>(rw, wih, wgw);
  gru_kernel<<<64, 192, 0, stream>>>(q, r, whh, bhh);
  top1_kernel<<<128, 256, 0, stream>>>(q, wgw, wgb);
  kernelE<<<313, 128, 0, stream>>>(emb, eb1, eb2, lng, lnb);
  kernelF<<<1024, 128, 0, stream>>>(q, r, pcb, pib, out);
}